// Round 9
// baseline (327.149 us; speedup 1.0000x reference)
//
#include <hip/hip_runtime.h>
#include <math.h>

#define S_LEN 512
#define D_DIM 64

typedef __attribute__((ext_vector_type(8))) short bf16x8;
typedef __attribute__((ext_vector_type(4))) float f32x4;
typedef __attribute__((ext_vector_type(4))) unsigned int u32x4;
typedef __attribute__((ext_vector_type(2))) __fp16 h16x2;   // matches cvt_pkrtz return
typedef __attribute__((ext_vector_type(4))) __fp16 h16x4;   // matches mfma V4h operand
typedef unsigned int u32;

__device__ __forceinline__ float pow2i(int e) {  // 2^e, e in normal range
    return __int_as_float((e + 127) << 23);
}
// (bf16(hi) << 16) | bf16(lo) — both values exactly representable in bf16
__device__ __forceinline__ u32 pack_bf2(float lo, float hi) {
    return __builtin_amdgcn_perm(__float_as_uint(hi), __float_as_uint(lo), 0x07060302u);
}

__device__ __forceinline__ f32x4 mfma1616(h16x4 a, h16x4 b, f32x4 c) {
    return __builtin_amdgcn_mfma_f32_16x16x16f16(a, b, c, 0, 0, 0);
}

// ============================================================================
// r3 skeleton (8 waves, wave-owns-16-rows, no cross-wave reductions) with the
// PV P-exchange ELIMINATED: QK's C-layout IS the B-frag layout of the K=16
// MFMA, so PV = mfma_f32_16x16x16_f16(A=V^T frag from LDS, B=quantized P in
// regs). No ds_write/lgkmcnt(0) round-trip per chunk. f16 PV is bit-exact
// (m_p <= 127, mv*2^(ev-7) exact in f16; f32 accumulate).
// ============================================================================
extern "C" __global__ void __launch_bounds__(512, 2)
mxattn(const float* __restrict__ gmq, const int* __restrict__ geq,
       const float* __restrict__ gmk, const int* __restrict__ gek,
       const float* __restrict__ gmv, const int* __restrict__ gev,
       float* __restrict__ gout)
{
    // K' = mk*2^(ek-7) bf16, fragment-linear for 16x16x32 A-frags:
    // tile tt at tt*2048; sub-k s at +s*1024; lane L 16B at +L*16
    // holds K'[t=tt*16+(L&15)][d=s*32+(L>>4)*8+j].
    __shared__ __attribute__((aligned(16))) short Ktile[32768];     // 64 KB
    // V' = mv*2^(ev-7) f16, fragment-linear for 16x16x16 A-frags (V^T):
    // tile (T,dt) at (T*4+dt)*512 bytes... (idx*512, idx = T*4+dt); lane L 8B
    // at +L*8 holds V'[t=T*16+(L>>4)*4+j][d=dt*16+(L&15)], j=0..3.
    __shared__ __attribute__((aligned(16))) short Vtile[32768];     // 64 KB

    const int b    = blockIdx.x;
    const int tid  = threadIdx.x;
    const int lane = tid & 63;
    const int wave = tid >> 6;
    const int l15  = lane & 15;
    const int lg   = lane >> 4;

    const float* mqb = gmq + (size_t)b * (S_LEN * D_DIM);
    const float* mkb = gmk + (size_t)b * (S_LEN * D_DIM);
    const float* mvb = gmv + (size_t)b * (S_LEN * D_DIM);
    const int* eqb = geq + b * S_LEN;
    const int* ekb = gek + b * S_LEN;
    const int* evb = gev + b * S_LEN;

    char* kb = (char*)Ktile;
    char* vb = (char*)Vtile;

    // ---------------- staging: K (bf16) + V^T (f16), one barrier ----------------
    #pragma unroll
    for (int i = 0; i < 4; ++i) {
        int tt = wave * 4 + i;
        int t = tt * 16 + l15;
        float ks = pow2i(ekb[t] - 7);
        const float* kp = mkb + t * 64 + lg * 8;
        f32x4 a0 = *(const f32x4*)(kp);
        f32x4 a1 = *(const f32x4*)(kp + 4);
        f32x4 a2 = *(const f32x4*)(kp + 32);
        f32x4 a3 = *(const f32x4*)(kp + 36);
        u32x4 w0 = { pack_bf2(a0[0] * ks, a0[1] * ks), pack_bf2(a0[2] * ks, a0[3] * ks),
                     pack_bf2(a1[0] * ks, a1[1] * ks), pack_bf2(a1[2] * ks, a1[3] * ks) };
        u32x4 w1 = { pack_bf2(a2[0] * ks, a2[1] * ks), pack_bf2(a2[2] * ks, a2[3] * ks),
                     pack_bf2(a3[0] * ks, a3[1] * ks), pack_bf2(a3[2] * ks, a3[3] * ks) };
        *(u32x4*)(kb + tt * 2048 + lane * 16) = w0;
        *(u32x4*)(kb + tt * 2048 + 1024 + lane * 16) = w1;
    }
    #pragma unroll
    for (int i = 0; i < 16; ++i) {
        int idx = wave * 16 + i;         // tile id: T = idx>>2, dt = idx&3
        int row0 = (idx >> 2) * 16 + lg * 4;
        int col  = (idx & 3) * 16 + l15;
        float v0 = mvb[(row0 + 0) * 64 + col] * pow2i(evb[row0 + 0] - 7);
        float v1 = mvb[(row0 + 1) * 64 + col] * pow2i(evb[row0 + 1] - 7);
        float v2 = mvb[(row0 + 2) * 64 + col] * pow2i(evb[row0 + 2] - 7);
        float v3 = mvb[(row0 + 3) * 64 + col] * pow2i(evb[row0 + 3] - 7);
        h16x2 p01 = __builtin_amdgcn_cvt_pkrtz(v0, v1);   // exact (int*pow2)
        h16x2 p23 = __builtin_amdgcn_cvt_pkrtz(v2, v3);
        h16x4 wv = { p01[0], p01[1], p23[0], p23[1] };
        *(h16x4*)(vb + idx * 512 + lane * 8) = wv;        // linear 512B write
    }
    float sqp[4];
    #pragma unroll
    for (int p = 0; p < 4; ++p) sqp[p] = pow2i(eqb[p * 128 + wave * 16 + l15] - 7);
    __syncthreads();

    const float L2E = 1.44269504088896340736f;

    for (int pass = 0; pass < 4; ++pass) {
        const int r0 = pass * 128 + wave * 16;

        // ---- Q B-frags (col = s = l15, k = d = lg*8+j), raw integer mantissas ----
        bf16x8 qa0, qa1;
        {
            const float* qp = mqb + (size_t)(r0 + l15) * 64 + lg * 8;
            f32x4 a0 = *(const f32x4*)(qp);
            f32x4 a1 = *(const f32x4*)(qp + 4);
            f32x4 a2 = *(const f32x4*)(qp + 32);
            f32x4 a3 = *(const f32x4*)(qp + 36);
            u32x4 q0 = { pack_bf2(a0[0], a0[1]), pack_bf2(a0[2], a0[3]),
                         pack_bf2(a1[0], a1[1]), pack_bf2(a1[2], a1[3]) };
            u32x4 q1 = { pack_bf2(a2[0], a2[1]), pack_bf2(a2[2], a2[3]),
                         pack_bf2(a3[0], a3[1]), pack_bf2(a3[2], a3[3]) };
            qa0 = *(bf16x8*)&q0;
            qa1 = *(bf16x8*)&q1;
        }

        // ---- QK^T swapped: acc[tt][j] = S[t = tt*16+lg*4+j][s = l15] ----
        f32x4 acc[32];
        #pragma unroll
        for (int tt = 0; tt < 32; ++tt) acc[tt] = f32x4{0.f, 0.f, 0.f, 0.f};
        #pragma unroll
        for (int tt = 0; tt < 32; ++tt) {
            bf16x8 kf0 = *(const bf16x8*)(kb + tt * 2048 + lane * 16);
            bf16x8 kf1 = *(const bf16x8*)(kb + tt * 2048 + 1024 + lane * 16);
            acc[tt] = __builtin_amdgcn_mfma_f32_16x16x32_bf16(kf0, qa0, acc[tt], 0, 0, 0);
            acc[tt] = __builtin_amdgcn_mfma_f32_16x16x32_bf16(kf1, qa1, acc[tt], 0, 0, 0);
        }

        // ---- row amax (scores >= 0), per s = l15 ----
        float am0 = 0.f, am1 = 0.f, am2 = 0.f, am3 = 0.f;
        #pragma unroll
        for (int tt = 0; tt < 32; ++tt) {
            am0 = fmaxf(am0, acc[tt][0]); am1 = fmaxf(am1, acc[tt][1]);
            am2 = fmaxf(am2, acc[tt][2]); am3 = fmaxf(am3, acc[tt][3]);
        }
        float amax = fmaxf(fmaxf(am0, am1), fmaxf(am2, am3));
        amax = fmaxf(amax, __shfl_xor(amax, 16));
        amax = fmaxf(amax, __shfl_xor(amax, 32));

        // ---- score quant scale: e_s = clip(floor(log2(amax*sq)), -8, 7) ----
        const float sq = sqp[pass];
        float as = fmaxf(amax * sq, 1.17549435e-38f);
        int es = (int)((__float_as_uint(as) >> 23) & 0xFFu) - 127;
        es = es < -8 ? -8 : (es > 7 ? 7 : es);
        const float c1 = sq * pow2i(7 - es);
        const float M = fminf(rintf(amax * c1), 127.f);   // row max of m (monotone)
        const float nML2E = -M * L2E;

        // ---- fused quant + exp (native v_exp) + row sum ----
        float s0 = 0.f, s1 = 0.f, s2 = 0.f, s3 = 0.f;
        #pragma unroll
        for (int tt = 0; tt < 32; ++tt) {
            f32x4 a = acc[tt];
            float m0 = fminf(rintf(a[0] * c1), 127.f);
            float m1 = fminf(rintf(a[1] * c1), 127.f);
            float m2 = fminf(rintf(a[2] * c1), 127.f);
            float m3 = fminf(rintf(a[3] * c1), 127.f);
            a[0] = exp2f(fmaf(m0, L2E, nML2E));
            a[1] = exp2f(fmaf(m1, L2E, nML2E));
            a[2] = exp2f(fmaf(m2, L2E, nML2E));
            a[3] = exp2f(fmaf(m3, L2E, nML2E));
            s0 += a[0]; s1 += a[1]; s2 += a[2]; s3 += a[3];
            acc[tt] = a;
        }
        float sum = (s0 + s1) + (s2 + s3);
        sum += __shfl_xor(sum, 16);
        sum += __shfl_xor(sum, 32);

        // ---- prob quant: max prob = 1/sum; fused scale ----
        float pm = fmaxf(1.0f / sum, 1.17549435e-38f);
        int ep = (int)((__float_as_uint(pm) >> 23) & 0xFFu) - 127;
        ep = ep < -8 ? -8 : (ep > 7 ? 7 : ep);
        const float sp = pow2i(7 - ep) / sum;      // m_p = rint(e * sp)
        const float osc = pow2i(ep - 7);           // ctx row scale (per s = l15)

        // ---- PV: quantize P per tile IN REGISTERS, feed K=16 MFMA directly ----
        // B-frag of 16x16x16 is exactly acc's C-layout (col=s=l15, k=lg*4+j).
        // A = V^T frag from LDS (b64). ctx^T: lane holds
        // ctx[s=l15][d = dt*16 + lg*4 + j].
        f32x4 ctx[4];
        #pragma unroll
        for (int dt = 0; dt < 4; ++dt) ctx[dt] = f32x4{0.f, 0.f, 0.f, 0.f};
        #pragma unroll
        for (int tt = 0; tt < 32; ++tt) {
            f32x4 a = acc[tt];
            float m0 = fminf(rintf(a[0] * sp), 127.f);
            float m1 = fminf(rintf(a[1] * sp), 127.f);
            float m2 = fminf(rintf(a[2] * sp), 127.f);
            float m3 = fminf(rintf(a[3] * sp), 127.f);
            h16x2 p01 = __builtin_amdgcn_cvt_pkrtz(m0, m1);   // exact (<=127 int)
            h16x2 p23 = __builtin_amdgcn_cvt_pkrtz(m2, m3);
            h16x4 pf = { p01[0], p01[1], p23[0], p23[1] };
            #pragma unroll
            for (int dt = 0; dt < 4; ++dt) {
                h16x4 vf = *(const h16x4*)(vb + (tt * 4 + dt) * 512 + lane * 8);
                ctx[dt] = mfma1616(vf, pf, ctx[dt]);
            }
        }

        // ---- epilogue: per s = l15 (no shuffles for osc), a4 over lg only ----
        float cv[4][4];
        float a4 = 0.f;
        #pragma unroll
        for (int dt = 0; dt < 4; ++dt)
            #pragma unroll
            for (int j = 0; j < 4; ++j) {
                float x = ctx[dt][j] * osc;
                cv[dt][j] = x;
                a4 = fmaxf(a4, fabsf(x));
            }
        a4 = fmaxf(a4, __shfl_xor(a4, 16));
        a4 = fmaxf(a4, __shfl_xor(a4, 32));
        float aa = fmaxf(a4, 1.17549435e-38f);
        int ec = (int)((__float_as_uint(aa) >> 23) & 0xFFu) - 127;
        ec = ec < -8 ? -8 : (ec > 7 ? 7 : ec);
        const float csc = pow2i(7 - ec);
        const float oo = pow2i(ec - 7);
        float* orow = gout + ((size_t)b * S_LEN + r0 + l15) * D_DIM + lg * 4;
        #pragma unroll
        for (int dt = 0; dt < 4; ++dt) {
            f32x4 ov;
            #pragma unroll
            for (int j = 0; j < 4; ++j) {
                float m = rintf(cv[dt][j] * csc);
                m = fminf(fmaxf(m, -128.f), 127.f);
                ov[j] = m * oo;
            }
            *(f32x4*)(orow + dt * 16) = ov;   // 16B vector store
        }
    }
}

extern "C" void kernel_launch(void* const* d_in, const int* in_sizes, int n_in,
                              void* d_out, int out_size, void* d_ws, size_t ws_size,
                              hipStream_t stream) {
    const float* mq = (const float*)d_in[0];
    const int*   eq = (const int*)d_in[1];
    const float* mk = (const float*)d_in[2];
    const int*   ek = (const int*)d_in[3];
    const float* mv = (const float*)d_in[4];
    const int*   ev = (const int*)d_in[5];
    float* out = (float*)d_out;
    int B = in_sizes[1] / S_LEN;   // 256
    mxattn<<<B, 512, 0, stream>>>(mq, eq, mk, ek, mv, ev, out);
}